// Round 10
// baseline (604.841 us; speedup 1.0000x reference)
//
#include <hip/hip_runtime.h>

typedef unsigned short u16;
typedef __attribute__((ext_vector_type(8))) short short8;
typedef __attribute__((ext_vector_type(4))) short short4v;
typedef __attribute__((ext_vector_type(4))) float f32x4;

#define DEVI static __device__ __forceinline__

DEVI u16 f2bf(float f) {
  unsigned u = __builtin_bit_cast(unsigned, f);
  u += 0x7FFFu + ((u >> 16) & 1u);   // RNE
  return (u16)(u >> 16);
}

DEVI float bf2f(u16 x) {
  unsigned u = ((unsigned)x) << 16;
  return __builtin_bit_cast(float, u);
}

DEVI unsigned cvtpk(float lo, float hi) {
  unsigned r;
  asm("v_cvt_pk_bf16_f32 %0, %1, %2" : "=v"(r) : "v"(lo), "v"(hi));
  return r;
}

DEVI void glds16(const void* g, void* l) {
  __builtin_amdgcn_global_load_lds(
      (const __attribute__((address_space(1))) unsigned*)g,
      (__attribute__((address_space(3))) unsigned*)l, 16, 0, 0);
}

// ---------------- all 8 weight transposes in ONE launch ---------------------
// 64x64 f32 tiles, float4 loads, short4 bf16 stores (G13: vectorized).
struct TSeg { const float* W; u16* WT; int K, N, tstart; };
struct TDesc { TSeg s[8]; };

__global__ void k_transpose_all(TDesc d) {
  __shared__ __align__(16) float t[64][68];   // 17.4 KB, 16B-aligned rows
  int bx = blockIdx.x;
  int si = 0;
#pragma unroll
  for (int k = 1; k < 8; ++k) si = (bx >= d.s[k].tstart) ? k : si;
  const float* W = d.s[si].W;
  u16* WT = d.s[si].WT;
  int K = d.s[si].K, N = d.s[si].N;
  int local = bx - d.s[si].tstart;
  int tpr = N >> 6;
  int n0 = (local % tpr) << 6;
  int k0 = (local / tpr) << 6;
  int tx = threadIdx.x;  // 0..15
  int ty = threadIdx.y;  // 0..15
#pragma unroll
  for (int r = 0; r < 4; ++r) {
    float4 v = *(const float4*)(W + (size_t)(k0 + ty * 4 + r) * N + n0 + tx * 4);
    *(float4*)&t[ty * 4 + r][tx * 4] = v;
  }
  __syncthreads();
#pragma unroll
  for (int r = 0; r < 4; ++r) {
    int nr = ty * 4 + r;
    short4v o;
    o[0] = (short)f2bf(t[tx * 4 + 0][nr]);
    o[1] = (short)f2bf(t[tx * 4 + 1][nr]);
    o[2] = (short)f2bf(t[tx * 4 + 2][nr]);
    o[3] = (short)f2bf(t[tx * 4 + 3][nr]);
    *(short4v*)(WT + (size_t)(n0 + nr) * K + k0 + tx * 4) = o;
  }
}

// ---------------- gather h rows at span starts/ends, cast to bf16 ----------
__global__ void k_gather(const float* __restrict__ h,
                         const int* __restrict__ span,
                         u16* __restrict__ xs, u16* __restrict__ xe) {
  int row = blockIdx.x;  // 0..511  (b*64+n)
  int b = row >> 6;
  int s = span[row * 2 + 0];
  int e = span[row * 2 + 1];
  const float* hs = h + ((size_t)b * 512 + s) * 768;
  const float* he = h + ((size_t)b * 512 + e) * 768;
  for (int d = threadIdx.x; d < 768; d += 256) {
    xs[(size_t)row * 768 + d] = f2bf(hs[d]);
    xe[(size_t)row * 768 + d] = f2bf(he[d]);
  }
}

// ---------------- unified bf16 MFMA GEMM (grouped + split-K) ---------------
// grid.z = ngroups*nsplit; z -> (g = z/nsplit, c = z%nsplit).
// A: M x K (lda), BT: N x K (ldb). k-chunk c covers [c*kLen, (c+1)*kLen).
// flags: 1=relu, 2=bf16 out, 4=f32 partial out at C + c*M*ldc (no bias).
__global__ __launch_bounds__(256)
void k_gemm(const u16* __restrict__ A0, const u16* __restrict__ A1, int lda,
            const u16* __restrict__ B0, const u16* __restrict__ B1, int ldb,
            const float* __restrict__ bias0, const float* __restrict__ bias1,
            void* __restrict__ C0, void* __restrict__ C1, int ldc,
            int kLen, int mtiles, int nsplit, int flags) {
  __shared__ __align__(16) u16 As[128 * 64];
  __shared__ __align__(16) u16 Bs[128 * 64];
  int z = blockIdx.z;
  int g = z / nsplit, c = z - g * nsplit;
  const u16* A = (g ? A1 : A0) + c * kLen;
  const u16* BT = (g ? B1 : B0) + c * kLen;
  const float* bias = g ? bias1 : bias0;
  void* C = g ? C1 : C0;

  int tid = threadIdx.x;
  int lane = tid & 63;
  int wave = tid >> 6;
  int wr = (wave >> 1) * 64, wc = (wave & 1) * 64;
  int bx = blockIdx.x;
  int m0 = (bx % mtiles) * 128;
  int n0 = (bx / mtiles) * 128;
  const int lr = lane & 15, hi = lane >> 4;

  f32x4 acc[4][4] = {};

  for (int k0 = 0; k0 < kLen; k0 += 64) {
#pragma unroll
    for (int it = 0; it < 4; ++it) {
      int s = it * 256 + tid;
      int row = s >> 3, gg = s & 7;
      int gc = (gg ^ (row & 7)) * 8;
      glds16(A + (size_t)(m0 + row) * lda + k0 + gc, (char*)As + s * 16);
      glds16(BT + (size_t)(n0 + row) * ldb + k0 + gc, (char*)Bs + s * 16);
    }
    __syncthreads();
#pragma unroll
    for (int kk = 0; kk < 2; ++kk) {
      short8 af[4], bf[4];
      int gk = kk * 4 + hi;
#pragma unroll
      for (int m = 0; m < 4; ++m) {
        int row = wr + m * 16 + lr;
        af[m] = *(const short8*)((const char*)As + row * 128 + ((gk ^ (row & 7)) * 16));
      }
#pragma unroll
      for (int n = 0; n < 4; ++n) {
        int row = wc + n * 16 + lr;
        bf[n] = *(const short8*)((const char*)Bs + row * 128 + ((gk ^ (row & 7)) * 16));
      }
#pragma unroll
      for (int m = 0; m < 4; ++m)
#pragma unroll
        for (int n = 0; n < 4; ++n)
          acc[m][n] = __builtin_amdgcn_mfma_f32_16x16x32_bf16(af[m], bf[n], acc[m][n], 0, 0, 0);
    }
    __syncthreads();
  }

  if (flags & 4) {
    float* P = (float*)C + (size_t)c * (mtiles * 128) * ldc;
#pragma unroll
    for (int n = 0; n < 4; ++n) {
      int col = n0 + wc + n * 16 + lr;
#pragma unroll
      for (int m = 0; m < 4; ++m)
#pragma unroll
        for (int r = 0; r < 4; ++r) {
          int row = m0 + wr + m * 16 + hi * 4 + r;
          P[(size_t)row * ldc + col] = acc[m][n][r];
        }
    }
  } else {
    bool relu = flags & 1;
#pragma unroll
    for (int n = 0; n < 4; ++n) {
      int col = n0 + wc + n * 16 + lr;
      float bv = bias ? bias[col] : 0.f;
#pragma unroll
      for (int m = 0; m < 4; ++m)
#pragma unroll
        for (int r = 0; r < 4; ++r) {
          int row = m0 + wr + m * 16 + hi * 4 + r;
          float v = acc[m][n][r] + bv;
          if (relu) v = fmaxf(v, 0.f);
          ((u16*)C)[(size_t)row * ldc + col] = f2bf(v);
        }
    }
  }
}

// ---------------- split-K finalizers ---------------------------------------
__global__ void k_fin_cat(const float* __restrict__ Ps, const float* __restrict__ Pe,
                          const float* __restrict__ b0, const float* __restrict__ b1,
                          u16* __restrict__ cat) {
  int t = blockIdx.x * 256 + threadIdx.x;        // 512*1536/4 = 196608
  int row = t / 384;
  int c4 = (t - row * 384) * 4;
  const float* P = Ps;
  const float* bias = b0;
  int lc = c4;
  if (c4 >= 768) { P = Pe; bias = b1; lc = c4 - 768; }
  f32x4 s = {};
#pragma unroll
  for (int ch = 0; ch < 4; ++ch)
    s += *(const f32x4*)(P + ((size_t)ch * 512 + row) * 768 + lc);
#pragma unroll
  for (int e = 0; e < 4; ++e)
    cat[(size_t)row * 1536 + c4 + e] = f2bf(fmaxf(s[e] + bias[lc + e], 0.f));
}

__global__ void k_fin_ent(const float* __restrict__ Po,
                          const float* __restrict__ bias,
                          u16* __restrict__ ent) {
  int t = blockIdx.x * 256 + threadIdx.x;        // 512*768/4 = 98304
  int row = t / 192;
  int c4 = (t - row * 192) * 4;
  f32x4 s = {};
#pragma unroll
  for (int ch = 0; ch < 8; ++ch)
    s += *(const f32x4*)(Po + ((size_t)ch * 512 + row) * 768 + c4);
#pragma unroll
  for (int e = 0; e < 4; ++e)
    ent[(size_t)row * 768 + c4 + e] = f2bf(s[e] + bias[c4 + e]);
}

// ---------------- fused pair GEMM: out = relu(U[i]+V[j]) @ Wr2 + br2 -------
// 4-phase deep-pipelined schedule (T3+T4+T5 port of the 8-phase template).
// M=32256, N=768, K=6144. BM=256, BN=192, BK=64, 512 thr / 8 waves (2Mx4N),
// wave tile 128x48 (acc 96 regs). LDS: A dbuf 64KB + B dbuf 48KB = 112KB,
// 1 block/CU, 2 waves/SIMD. Grid 126x4 = 504 = 8*63 (even 2-round tail).
// Per K-step: ph0{issue UV(t+1); bf+af(m0-3,kk0); MFMA} ph1{issue B-glds(t+1);
// af(m4-7,kk0); MFMA} ph2{build A(t+1)->other buf; bf+af(m0-3,kk1); MFMA}
// ph3{af(m4-7,kk1); MFMA; __syncthreads}. Raw s_barrier pairs per phase;
// glds drain at step-end sync (issued 3 phases earlier -> near-free).
__global__ __launch_bounds__(512, 2)
void k_pair_gemm(const u16* __restrict__ U, const u16* __restrict__ V,
                 const u16* __restrict__ Wr2T,  // 768 x 6144 bf16
                 const float* __restrict__ br2,
                 float* __restrict__ out) {
  __shared__ __align__(16) u16 As[2][256 * 64];   // 64 KB
  __shared__ __align__(16) u16 Bs[2][192 * 64];   // 48 KB
  int tid = threadIdx.x;
  int lane = tid & 63;
  int wave = tid >> 6;          // 0..7
  int wr = (wave >> 2) * 128;   // 0,128
  int wc = (wave & 3) * 48;     // 0,48,96,144
  const int lr = lane & 15, hi = lane >> 4;

  // XCD swizzle: nwg = 504 = 8*63 (divisible -> simple bijective form)
  int orig = blockIdx.x;
  int wgid = (orig & 7) * 63 + (orig >> 3);
  int mt = wgid % 126;
  int nt = wgid / 126;
  int m0 = mt * 256, n0 = nt * 192;

  // A-build mapping: thread owns row r (0..255), half q (32 cols of 64)
  int r = tid >> 1, q = tid & 1;
  int mrow = m0 + r;
  int b = mrow / 4032;
  int p = mrow - b * 4032;
  int i = p / 63;
  int j0 = p - i * 63;
  int j = j0 + (j0 >= i ? 1 : 0);
  const u16* uR = U + (size_t)(b * 64 + i) * 6144 + q * 32;
  const u16* vR = V + (size_t)(b * 64 + j) * 6144 + q * 32;

  auto stageB = [&](int t, int buf) {
#pragma unroll
    for (int it = 0; it < 3; ++it) {
      int s = it * 512 + tid;      // 1536 granules of the 192x64 tile
      int row = s >> 3, g = s & 7;
      int gc = (g ^ (row & 7)) * 8;
      glds16(Wr2T + (size_t)(n0 + row) * 6144 + t * 64 + gc,
             (char*)Bs[buf] + s * 16);
    }
  };

  f32x4 accL[4][3] = {};   // m 0..3
  f32x4 accH[4][3] = {};   // m 4..7

  // prologue: A(0) built -> As[0]; B(0) staged -> Bs[0]
  {
    short8 uu[4], vv[4];
#pragma unroll
    for (int g = 0; g < 4; ++g) {
      uu[g] = *(const short8*)(uR + g * 8);
      vv[g] = *(const short8*)(vR + g * 8);
    }
    char* ab = (char*)As[0] + r * 128;
#pragma unroll
    for (int g = 0; g < 4; ++g) {
      unsigned w[4];
#pragma unroll
      for (int e = 0; e < 4; ++e)
        w[e] = cvtpk(fmaxf(bf2f((u16)uu[g][2 * e]) + bf2f((u16)vv[g][2 * e]), 0.f),
                     fmaxf(bf2f((u16)uu[g][2 * e + 1]) + bf2f((u16)vv[g][2 * e + 1]), 0.f));
      *(uint4*)(ab + (((q * 4 + g) ^ (r & 7)) * 16)) = *(uint4*)w;
    }
    stageB(0, 0);
  }
  __syncthreads();

  for (int t = 0; t < 96; ++t) {
    const u16* Ac = As[t & 1];
    const u16* Bc = Bs[t & 1];
    bool pf = (t + 1 < 96);
    int gk0 = hi, gk1 = 4 + hi;

    auto rdA = [&](int m, int gk) -> short8 {
      int row = wr + m * 16 + lr;
      return *(const short8*)((const char*)Ac + row * 128 + ((gk ^ (row & 7)) * 16));
    };
    auto rdB = [&](int n, int gk) -> short8 {
      int row = wc + n * 16 + lr;
      return *(const short8*)((const char*)Bc + row * 128 + ((gk ^ (row & 7)) * 16));
    };

    short8 uu[4], vv[4];
    short8 bfr[3], af[4];

    // ---- ph0: issue UV(t+1); frags (m0..3, kk0); MFMA
    if (pf) {
      const u16* up = uR + (size_t)(t + 1) * 64;
      const u16* vp = vR + (size_t)(t + 1) * 64;
#pragma unroll
      for (int g = 0; g < 4; ++g) {
        uu[g] = *(const short8*)(up + g * 8);
        vv[g] = *(const short8*)(vp + g * 8);
      }
    }
    bfr[0] = rdB(0, gk0); bfr[1] = rdB(1, gk0); bfr[2] = rdB(2, gk0);
    af[0] = rdA(0, gk0); af[1] = rdA(1, gk0); af[2] = rdA(2, gk0); af[3] = rdA(3, gk0);
    asm volatile("s_barrier" ::: "memory");
    __builtin_amdgcn_sched_barrier(0);
    __builtin_amdgcn_s_setprio(1);
#pragma unroll
    for (int m = 0; m < 4; ++m)
#pragma unroll
      for (int n = 0; n < 3; ++n)
        accL[m][n] = __builtin_amdgcn_mfma_f32_16x16x32_bf16(af[m], bfr[n], accL[m][n], 0, 0, 0);
    __builtin_amdgcn_s_setprio(0);
    asm volatile("s_barrier" ::: "memory");

    // ---- ph1: issue B-glds(t+1); frags (m4..7, kk0); MFMA
    if (pf) stageB(t + 1, (t + 1) & 1);
    af[0] = rdA(4, gk0); af[1] = rdA(5, gk0); af[2] = rdA(6, gk0); af[3] = rdA(7, gk0);
    asm volatile("s_barrier" ::: "memory");
    __builtin_amdgcn_sched_barrier(0);
    __builtin_amdgcn_s_setprio(1);
#pragma unroll
    for (int m = 0; m < 4; ++m)
#pragma unroll
      for (int n = 0; n < 3; ++n)
        accH[m][n] = __builtin_amdgcn_mfma_f32_16x16x32_bf16(af[m], bfr[n], accH[m][n], 0, 0, 0);
    __builtin_amdgcn_s_setprio(0);
    asm volatile("s_barrier" ::: "memory");

    // ---- ph2: build+write A(t+1) to other buf; frags (m0..3, kk1); MFMA
    if (pf) {
      char* ab = (char*)As[(t + 1) & 1] + r * 128;
#pragma unroll
      for (int g = 0; g < 4; ++g) {
        unsigned w[4];
#pragma unroll
        for (int e = 0; e < 4; ++e)
          w[e] = cvtpk(fmaxf(bf2f((u16)uu[g][2 * e]) + bf2f((u16)vv[g][2 * e]), 0.f),
                       fmaxf(bf2f((u16)uu[g][2 * e + 1]) + bf2f((u16)vv[g][2 * e + 1]), 0.f));
        *(uint4*)(ab + (((q * 4 + g) ^ (r & 7)) * 16)) = *(uint4*)w;
      }
    }
    bfr[0] = rdB(0, gk1); bfr[1] = rdB(1, gk1); bfr[2] = rdB(2, gk1);
    af[0] = rdA(0, gk1); af[1] = rdA(1, gk1); af[2] = rdA(2, gk1); af[3] = rdA(3, gk1);
    asm volatile("s_barrier" ::: "memory");
    __builtin_amdgcn_sched_barrier(0);
    __builtin_amdgcn_s_setprio(1);
#pragma unroll
    for (int m = 0; m < 4; ++m)
#pragma unroll
      for (int n = 0; n < 3; ++n)
        accL[m][n] = __builtin_amdgcn_mfma_f32_16x16x32_bf16(af[m], bfr[n], accL[m][n], 0, 0, 0);
    __builtin_amdgcn_s_setprio(0);
    asm volatile("s_barrier" ::: "memory");

    // ---- ph3: frags (m4..7, kk1); MFMA; step-end full sync (drains glds+writes)
    af[0] = rdA(4, gk1); af[1] = rdA(5, gk1); af[2] = rdA(6, gk1); af[3] = rdA(7, gk1);
    asm volatile("s_barrier" ::: "memory");
    __builtin_amdgcn_sched_barrier(0);
    __builtin_amdgcn_s_setprio(1);
#pragma unroll
    for (int m = 0; m < 4; ++m)
#pragma unroll
      for (int n = 0; n < 3; ++n)
        accH[m][n] = __builtin_amdgcn_mfma_f32_16x16x32_bf16(af[m], bfr[n], accH[m][n], 0, 0, 0);
    __builtin_amdgcn_s_setprio(0);
    __syncthreads();
  }

#pragma unroll
  for (int n = 0; n < 3; ++n) {
    int col = n0 + wc + n * 16 + lr;
    float bv = br2[col];
#pragma unroll
    for (int m = 0; m < 4; ++m)
#pragma unroll
      for (int rg = 0; rg < 4; ++rg) {
        int rowL = m0 + wr + m * 16 + hi * 4 + rg;
        out[(size_t)rowL * 768 + col] = accL[m][n][rg] + bv;
        out[(size_t)(rowL + 64) * 768 + col] = accH[m][n][rg] + bv;
      }
  }
}

// ---------------- workspace layout (bytes) ---------------------------------
constexpr size_t OFF_Ws1T = 0;
constexpr size_t OFF_Ws2T = OFF_Ws1T + (size_t)3072 * 768 * 2;
constexpr size_t OFF_We1T = OFF_Ws2T + (size_t)768 * 3072 * 2;
constexpr size_t OFF_We2T = OFF_We1T + (size_t)3072 * 768 * 2;
constexpr size_t OFF_Wo1T = OFF_We2T + (size_t)768 * 3072 * 2;
constexpr size_t OFF_Wo2T = OFF_Wo1T + (size_t)6144 * 1536 * 2;
constexpr size_t OFF_Wr1T = OFF_Wo2T + (size_t)768 * 6144 * 2;
constexpr size_t OFF_Wr2T = OFF_Wr1T + (size_t)6144 * 1536 * 2;
constexpr size_t OFF_XS   = OFF_Wr2T + (size_t)768 * 6144 * 2;
constexpr size_t OFF_XE   = OFF_XS + (size_t)512 * 768 * 2;
constexpr size_t OFF_HS1  = OFF_XE + (size_t)512 * 768 * 2;
constexpr size_t OFF_HE1  = OFF_HS1 + (size_t)512 * 3072 * 2;
constexpr size_t OFF_CAT  = OFF_HE1 + (size_t)512 * 3072 * 2;
constexpr size_t OFF_ENTH = OFF_CAT + (size_t)512 * 1536 * 2;
constexpr size_t OFF_ENT  = OFF_ENTH + (size_t)512 * 6144 * 2;
constexpr size_t OFF_U    = OFF_ENT + (size_t)512 * 768 * 2;
constexpr size_t OFF_V    = OFF_U + (size_t)512 * 6144 * 2;
// split-K partials: Ps(4ch)+Pe(4ch) = 12.6MB; Po(8ch) overlaps both (dead by then)
constexpr size_t OFF_PS   = OFF_V + (size_t)512 * 6144 * 2;
constexpr size_t OFF_PE   = OFF_PS + (size_t)4 * 512 * 768 * 4;
constexpr size_t OFF_PO   = OFF_PS;

extern "C" void kernel_launch(void* const* d_in, const int* in_sizes, int n_in,
                              void* d_out, int out_size, void* d_ws, size_t ws_size,
                              hipStream_t stream) {
  const float* h = (const float*)d_in[0];
  const int* span = (const int*)d_in[1];   // int inputs arrive as int32
  const float* Ws1 = (const float*)d_in[2];
  const float* bs1 = (const float*)d_in[3];
  const float* Ws2 = (const float*)d_in[4];
  const float* bs2 = (const float*)d_in[5];
  const float* We1 = (const float*)d_in[6];
  const float* be1 = (const float*)d_in[7];
  const float* We2 = (const float*)d_in[8];
  const float* be2 = (const float*)d_in[9];
  const float* Wo1 = (const float*)d_in[10];
  const float* bo1 = (const float*)d_in[11];
  const float* Wo2 = (const float*)d_in[12];
  const float* bo2 = (const float*)d_in[13];
  const float* Wr1 = (const float*)d_in[14];
  const float* br1 = (const float*)d_in[15];
  const float* Wr2 = (const float*)d_in[16];
  const float* br2 = (const float*)d_in[17];

  char* ws = (char*)d_ws;
  u16* Ws1T = (u16*)(ws + OFF_Ws1T);
  u16* Ws2T = (u16*)(ws + OFF_Ws2T);
  u16* We1T = (u16*)(ws + OFF_We1T);
  u16* We2T = (u16*)(ws + OFF_We2T);
  u16* Wo1T = (u16*)(ws + OFF_Wo1T);
  u16* Wo2T = (u16*)(ws + OFF_Wo2T);
  u16* Wr1T = (u16*)(ws + OFF_Wr1T);
  u16* Wr2T = (u16*)(ws + OFF_Wr2T);
  u16* xs   = (u16*)(ws + OFF_XS);
  u16* xe   = (u16*)(ws + OFF_XE);
  u16* hs1  = (u16*)(ws + OFF_HS1);
  u16* he1  = (u16*)(ws + OFF_HE1);
  u16* cat  = (u16*)(ws + OFF_CAT);
  u16* enth = (u16*)(ws + OFF_ENTH);
  u16* ent  = (u16*)(ws + OFF_ENT);
  u16* Ub   = (u16*)(ws + OFF_U);
  u16* Vb   = (u16*)(ws + OFF_V);
  float* Ps = (float*)(ws + OFF_PS);
  float* Pe = (float*)(ws + OFF_PE);
  float* Po = (float*)(ws + OFF_PO);

  // one merged transpose launch (tstart = cumulative 64x64 tile counts)
  TDesc td;
  td.s[0] = {Ws1, Ws1T,  768, 3072,    0};
  td.s[1] = {Ws2, Ws2T, 3072,  768,  576};
  td.s[2] = {We1, We1T,  768, 3072, 1152};
  td.s[3] = {We2, We2T, 3072,  768, 1728};
  td.s[4] = {Wo1, Wo1T, 1536, 6144, 2304};
  td.s[5] = {Wo2, Wo2T, 6144,  768, 4608};
  td.s[6] = {Wr1, Wr1T, 1536, 6144, 5760};
  td.s[7] = {Wr2, Wr2T, 6144,  768, 8064};
  k_transpose_all<<<9216, dim3(16, 16), 0, stream>>>(td);

  k_gather<<<512, 256, 0, stream>>>(h, span, xs, xe);

  // GEMM1 s&e (grouped): hs1 = relu(xs@Ws1+bs1), he1 = relu(xe@We1+be1)
  k_gemm<<<dim3(96, 1, 2), 256, 0, stream>>>(xs, xe, 768, Ws1T, We1T, 768,
      bs1, be1, hs1, he1, 3072, 768, 4, 1, 1 | 2);
  // GEMM2 s&e split-K x4 -> f32 partials
  k_gemm<<<dim3(24, 1, 8), 256, 0, stream>>>(hs1, he1, 3072, Ws2T, We2T, 3072,
      nullptr, nullptr, Ps, Pe, 768, 768, 4, 4, 4);
  k_fin_cat<<<768, 256, 0, stream>>>(Ps, Pe, bs2, be2, cat);
  // entity MLP layer 1
  k_gemm<<<dim3(192, 1, 1), 256, 0, stream>>>(cat, cat, 1536, Wo1T, Wo1T, 1536,
      bo1, bo1, enth, enth, 6144, 1536, 4, 1, 1 | 2);
  // entity MLP layer 2 split-K x8 -> f32 partials
  k_gemm<<<dim3(24, 1, 8), 256, 0, stream>>>(enth, enth, 6144, Wo2T, Wo2T, 6144,
      nullptr, nullptr, Po, Po, 768, 768, 4, 8, 4);
  k_fin_ent<<<384, 256, 0, stream>>>(Po, bo2, ent);
  // low-rank pair projections (grouped): U = ent@Wr1[:768]+br1 ; V = ent@Wr1[768:]
  k_gemm<<<dim3(192, 1, 2), 256, 0, stream>>>(ent, ent, 768, Wr1T, Wr1T + 768, 1536,
      br1, nullptr, Ub, Vb, 6144, 768, 4, 1, 2);
  // fused final pair GEMM -> out (f32)
  k_pair_gemm<<<504, 512, 0, stream>>>(Ub, Vb, Wr2T, br2, (float*)d_out);
}

// Round 11
// 458.162 us; speedup vs baseline: 1.3201x; 1.3201x over previous
//
#include <hip/hip_runtime.h>

typedef unsigned short u16;
typedef __attribute__((ext_vector_type(8))) short short8;
typedef __attribute__((ext_vector_type(4))) short short4v;
typedef __attribute__((ext_vector_type(4))) float f32x4;

#define DEVI static __device__ __forceinline__

DEVI u16 f2bf(float f) {
  unsigned u = __builtin_bit_cast(unsigned, f);
  u += 0x7FFFu + ((u >> 16) & 1u);   // RNE
  return (u16)(u >> 16);
}

DEVI float bf2f(u16 x) {
  unsigned u = ((unsigned)x) << 16;
  return __builtin_bit_cast(float, u);
}

DEVI unsigned cvtpk(float lo, float hi) {
  unsigned r;
  asm("v_cvt_pk_bf16_f32 %0, %1, %2" : "=v"(r) : "v"(lo), "v"(hi));
  return r;
}

DEVI void glds16(const void* g, void* l) {
  __builtin_amdgcn_global_load_lds(
      (const __attribute__((address_space(1))) unsigned*)g,
      (__attribute__((address_space(3))) unsigned*)l, 16, 0, 0);
}

// ---------------- all 8 weight transposes in ONE launch ---------------------
// 64x64 f32 tiles, float4 loads, short4 bf16 stores (G13: vectorized).
struct TSeg { const float* W; u16* WT; int K, N, tstart; };
struct TDesc { TSeg s[8]; };

__global__ void k_transpose_all(TDesc d) {
  __shared__ __align__(16) float t[64][68];   // 17.4 KB, 16B-aligned rows
  int bx = blockIdx.x;
  int si = 0;
#pragma unroll
  for (int k = 1; k < 8; ++k) si = (bx >= d.s[k].tstart) ? k : si;
  const float* W = d.s[si].W;
  u16* WT = d.s[si].WT;
  int K = d.s[si].K, N = d.s[si].N;
  int local = bx - d.s[si].tstart;
  int tpr = N >> 6;
  int n0 = (local % tpr) << 6;
  int k0 = (local / tpr) << 6;
  int tx = threadIdx.x;  // 0..15
  int ty = threadIdx.y;  // 0..15
#pragma unroll
  for (int r = 0; r < 4; ++r) {
    float4 v = *(const float4*)(W + (size_t)(k0 + ty * 4 + r) * N + n0 + tx * 4);
    *(float4*)&t[ty * 4 + r][tx * 4] = v;
  }
  __syncthreads();
#pragma unroll
  for (int r = 0; r < 4; ++r) {
    int nr = ty * 4 + r;
    short4v o;
    o[0] = (short)f2bf(t[tx * 4 + 0][nr]);
    o[1] = (short)f2bf(t[tx * 4 + 1][nr]);
    o[2] = (short)f2bf(t[tx * 4 + 2][nr]);
    o[3] = (short)f2bf(t[tx * 4 + 3][nr]);
    *(short4v*)(WT + (size_t)(n0 + nr) * K + k0 + tx * 4) = o;
  }
}

// ---------------- gather h rows at span starts/ends, cast to bf16 ----------
__global__ void k_gather(const float* __restrict__ h,
                         const int* __restrict__ span,
                         u16* __restrict__ xs, u16* __restrict__ xe) {
  int row = blockIdx.x;  // 0..511  (b*64+n)
  int b = row >> 6;
  int s = span[row * 2 + 0];
  int e = span[row * 2 + 1];
  const float* hs = h + ((size_t)b * 512 + s) * 768;
  const float* he = h + ((size_t)b * 512 + e) * 768;
  for (int d = threadIdx.x; d < 768; d += 256) {
    xs[(size_t)row * 768 + d] = f2bf(hs[d]);
    xe[(size_t)row * 768 + d] = f2bf(he[d]);
  }
}

// ---------------- unified bf16 MFMA GEMM (grouped + split-K) ---------------
// grid.z = ngroups*nsplit; z -> (g = z/nsplit, c = z%nsplit).
// A: M x K (lda), BT: N x K (ldb). k-chunk c covers [c*kLen, (c+1)*kLen).
// flags: 1=relu, 2=bf16 out, 4=f32 partial out at C + c*M*ldc (no bias).
__global__ __launch_bounds__(256)
void k_gemm(const u16* __restrict__ A0, const u16* __restrict__ A1, int lda,
            const u16* __restrict__ B0, const u16* __restrict__ B1, int ldb,
            const float* __restrict__ bias0, const float* __restrict__ bias1,
            void* __restrict__ C0, void* __restrict__ C1, int ldc,
            int kLen, int mtiles, int nsplit, int flags) {
  __shared__ __align__(16) u16 As[128 * 64];
  __shared__ __align__(16) u16 Bs[128 * 64];
  int z = blockIdx.z;
  int g = z / nsplit, c = z - g * nsplit;
  const u16* A = (g ? A1 : A0) + c * kLen;
  const u16* BT = (g ? B1 : B0) + c * kLen;
  const float* bias = g ? bias1 : bias0;
  void* C = g ? C1 : C0;

  int tid = threadIdx.x;
  int lane = tid & 63;
  int wave = tid >> 6;
  int wr = (wave >> 1) * 64, wc = (wave & 1) * 64;
  int bx = blockIdx.x;
  int m0 = (bx % mtiles) * 128;
  int n0 = (bx / mtiles) * 128;
  const int lr = lane & 15, hi = lane >> 4;

  f32x4 acc[4][4] = {};

  for (int k0 = 0; k0 < kLen; k0 += 64) {
#pragma unroll
    for (int it = 0; it < 4; ++it) {
      int s = it * 256 + tid;
      int row = s >> 3, gg = s & 7;
      int gc = (gg ^ (row & 7)) * 8;
      glds16(A + (size_t)(m0 + row) * lda + k0 + gc, (char*)As + s * 16);
      glds16(BT + (size_t)(n0 + row) * ldb + k0 + gc, (char*)Bs + s * 16);
    }
    __syncthreads();
#pragma unroll
    for (int kk = 0; kk < 2; ++kk) {
      short8 af[4], bf[4];
      int gk = kk * 4 + hi;
#pragma unroll
      for (int m = 0; m < 4; ++m) {
        int row = wr + m * 16 + lr;
        af[m] = *(const short8*)((const char*)As + row * 128 + ((gk ^ (row & 7)) * 16));
      }
#pragma unroll
      for (int n = 0; n < 4; ++n) {
        int row = wc + n * 16 + lr;
        bf[n] = *(const short8*)((const char*)Bs + row * 128 + ((gk ^ (row & 7)) * 16));
      }
#pragma unroll
      for (int m = 0; m < 4; ++m)
#pragma unroll
        for (int n = 0; n < 4; ++n)
          acc[m][n] = __builtin_amdgcn_mfma_f32_16x16x32_bf16(af[m], bf[n], acc[m][n], 0, 0, 0);
    }
    __syncthreads();
  }

  if (flags & 4) {
    float* P = (float*)C + (size_t)c * (mtiles * 128) * ldc;
#pragma unroll
    for (int n = 0; n < 4; ++n) {
      int col = n0 + wc + n * 16 + lr;
#pragma unroll
      for (int m = 0; m < 4; ++m)
#pragma unroll
        for (int r = 0; r < 4; ++r) {
          int row = m0 + wr + m * 16 + hi * 4 + r;
          P[(size_t)row * ldc + col] = acc[m][n][r];
        }
    }
  } else {
    bool relu = flags & 1;
#pragma unroll
    for (int n = 0; n < 4; ++n) {
      int col = n0 + wc + n * 16 + lr;
      float bv = bias ? bias[col] : 0.f;
#pragma unroll
      for (int m = 0; m < 4; ++m)
#pragma unroll
        for (int r = 0; r < 4; ++r) {
          int row = m0 + wr + m * 16 + hi * 4 + r;
          float v = acc[m][n][r] + bv;
          if (relu) v = fmaxf(v, 0.f);
          ((u16*)C)[(size_t)row * ldc + col] = f2bf(v);
        }
    }
  }
}

// ---------------- split-K finalizers ---------------------------------------
__global__ void k_fin_cat(const float* __restrict__ Ps, const float* __restrict__ Pe,
                          const float* __restrict__ b0, const float* __restrict__ b1,
                          u16* __restrict__ cat) {
  int t = blockIdx.x * 256 + threadIdx.x;        // 512*1536/4 = 196608
  int row = t / 384;
  int c4 = (t - row * 384) * 4;
  const float* P = Ps;
  const float* bias = b0;
  int lc = c4;
  if (c4 >= 768) { P = Pe; bias = b1; lc = c4 - 768; }
  f32x4 s = {};
#pragma unroll
  for (int ch = 0; ch < 4; ++ch)
    s += *(const f32x4*)(P + ((size_t)ch * 512 + row) * 768 + lc);
#pragma unroll
  for (int e = 0; e < 4; ++e)
    cat[(size_t)row * 1536 + c4 + e] = f2bf(fmaxf(s[e] + bias[lc + e], 0.f));
}

__global__ void k_fin_ent(const float* __restrict__ Po,
                          const float* __restrict__ bias,
                          u16* __restrict__ ent) {
  int t = blockIdx.x * 256 + threadIdx.x;        // 512*768/4 = 98304
  int row = t / 192;
  int c4 = (t - row * 192) * 4;
  f32x4 s = {};
#pragma unroll
  for (int ch = 0; ch < 8; ++ch)
    s += *(const f32x4*)(Po + ((size_t)ch * 512 + row) * 768 + c4);
#pragma unroll
  for (int e = 0; e < 4; ++e)
    ent[(size_t)row * 768 + c4 + e] = f2bf(s[e] + bias[c4 + e]);
}

// ---------------- fused pair GEMM: out = relu(U[i]+V[j]) @ Wr2 + br2 -------
// r3-proven pipeline, tail-balanced geometry: M=32256, N=768, K=6144.
// BM=128, BN=192, BK=64, 512 thr / 8 waves (2Mx4N), wave tile 64x48
// (acc 48 regs). LDS = A 16KB + B dbuf 2x24KB = 64KB -> 2 blocks/CU,
// 512 co-resident. Grid 252x4 = 1008 blocks -> 1008/1024 = 98.4% fill
// over 2 rounds (vs r3's 756/1024 = 74%). Pipeline identical to r3:
// UV(t+1)+B(t+1) prefetch between barriers; barrier #2 = raw s_barrier
// + lgkmcnt(0) only (no vmcnt drain).
__global__ __launch_bounds__(512, 4)
void k_pair_gemm(const u16* __restrict__ U, const u16* __restrict__ V,
                 const u16* __restrict__ Wr2T,  // 768 x 6144 bf16
                 const float* __restrict__ br2,
                 float* __restrict__ out) {
  __shared__ __align__(16) u16 As[128 * 64];       // 16 KB
  __shared__ __align__(16) u16 Bs[2][192 * 64];    // 48 KB
  int tid = threadIdx.x;
  int lane = tid & 63;
  int wave = tid >> 6;          // 0..7
  int wr = (wave >> 2) * 64;    // 0,64
  int wc = (wave & 3) * 48;     // 0,48,96,144
  const int lr = lane & 15, hi = lane >> 4;

  // XCD swizzle: nwg = 1008 = 8*126 (divisible -> simple bijective form)
  int orig = blockIdx.x;
  int wgid = (orig & 7) * 126 + (orig >> 3);
  int mt = wgid % 252;
  int nt = wgid / 252;          // 0..3
  int m0 = mt * 128, n0 = nt * 192;

  // A-build mapping: thread owns row r, col-group q (16 cols of 64)
  int r = tid >> 2, q = tid & 3;
  int mrow = m0 + r;
  int b = mrow / 4032;
  int p = mrow - b * 4032;
  int i = p / 63;
  int j0 = p - i * 63;
  int j = j0 + (j0 >= i ? 1 : 0);
  const u16* uR = U + (size_t)(b * 64 + i) * 6144 + q * 16;
  const u16* vR = V + (size_t)(b * 64 + j) * 6144 + q * 16;
  char* aw0 = (char*)As + r * 128 + (((q * 2 + 0) ^ (r & 7)) * 16);
  char* aw1 = (char*)As + r * 128 + (((q * 2 + 1) ^ (r & 7)) * 16);

  f32x4 acc[4][3] = {};

  auto stageB = [&](int t, int buf) {
#pragma unroll
    for (int it = 0; it < 3; ++it) {
      int s = it * 512 + tid;      // 1536 granules of the 192x64 tile
      int row = s >> 3, g = s & 7;
      int gc = (g ^ (row & 7)) * 8;
      glds16(Wr2T + (size_t)(n0 + row) * 6144 + t * 64 + gc,
             (char*)Bs[buf] + s * 16);
    }
  };

  // prologue: B(0) staged, UV(0) in regs
  stageB(0, 0);
  short8 ua = *(const short8*)(uR);
  short8 ub = *(const short8*)(uR + 8);
  short8 vva = *(const short8*)(vR);
  short8 vvb = *(const short8*)(vR + 8);

  for (int t = 0; t < 96; ++t) {
    // build A(t) fragment in regs (16 elems -> 8 packed u32)
    unsigned w0[4], w1[4];
#pragma unroll
    for (int e = 0; e < 4; ++e) {
      float a0 = fmaxf(bf2f((u16)ua[2 * e])     + bf2f((u16)vva[2 * e]), 0.f);
      float a1 = fmaxf(bf2f((u16)ua[2 * e + 1]) + bf2f((u16)vva[2 * e + 1]), 0.f);
      w0[e] = cvtpk(a0, a1);
      float b0 = fmaxf(bf2f((u16)ub[2 * e])     + bf2f((u16)vvb[2 * e]), 0.f);
      float b1 = fmaxf(bf2f((u16)ub[2 * e + 1]) + bf2f((u16)vvb[2 * e + 1]), 0.f);
      w1[e] = cvtpk(b0, b1);
    }
    __syncthreads();                     // #1: all reads of As/Bs[t&1] done; B(t) drained
    *(uint4*)aw0 = *(uint4*)w0;          // swizzled A writes
    *(uint4*)aw1 = *(uint4*)w1;
    if (t + 1 < 96) {                    // prefetch t+1 (flies across MFMA(t))
      ua  = *(const short8*)(uR + (t + 1) * 64);
      ub  = *(const short8*)(uR + (t + 1) * 64 + 8);
      vva = *(const short8*)(vR + (t + 1) * 64);
      vvb = *(const short8*)(vR + (t + 1) * 64 + 8);
      stageB(t + 1, (t + 1) & 1);
    }
    asm volatile("s_waitcnt lgkmcnt(0)\n\ts_barrier" ::: "memory");  // #2: no vmcnt drain
    __builtin_amdgcn_sched_barrier(0);

    const u16* Bc = Bs[t & 1];
#pragma unroll
    for (int kk = 0; kk < 2; ++kk) {
      short8 af[4], bf[3];
      int gk = kk * 4 + hi;
#pragma unroll
      for (int m = 0; m < 4; ++m) {
        int row = wr + m * 16 + lr;
        af[m] = *(const short8*)((const char*)As + row * 128 + ((gk ^ (row & 7)) * 16));
      }
#pragma unroll
      for (int n = 0; n < 3; ++n) {
        int row = wc + n * 16 + lr;
        bf[n] = *(const short8*)((const char*)Bc + row * 128 + ((gk ^ (row & 7)) * 16));
      }
#pragma unroll
      for (int m = 0; m < 4; ++m)
#pragma unroll
        for (int n = 0; n < 3; ++n)
          acc[m][n] = __builtin_amdgcn_mfma_f32_16x16x32_bf16(af[m], bf[n], acc[m][n], 0, 0, 0);
    }
  }

#pragma unroll
  for (int n = 0; n < 3; ++n) {
    int col = n0 + wc + n * 16 + lr;
    float bv = br2[col];
#pragma unroll
    for (int m = 0; m < 4; ++m)
#pragma unroll
      for (int rg = 0; rg < 4; ++rg) {
        int row = m0 + wr + m * 16 + hi * 4 + rg;
        out[(size_t)row * 768 + col] = acc[m][n][rg] + bv;
      }
  }
}

// ---------------- workspace layout (bytes) ---------------------------------
constexpr size_t OFF_Ws1T = 0;
constexpr size_t OFF_Ws2T = OFF_Ws1T + (size_t)3072 * 768 * 2;
constexpr size_t OFF_We1T = OFF_Ws2T + (size_t)768 * 3072 * 2;
constexpr size_t OFF_We2T = OFF_We1T + (size_t)3072 * 768 * 2;
constexpr size_t OFF_Wo1T = OFF_We2T + (size_t)768 * 3072 * 2;
constexpr size_t OFF_Wo2T = OFF_Wo1T + (size_t)6144 * 1536 * 2;
constexpr size_t OFF_Wr1T = OFF_Wo2T + (size_t)768 * 6144 * 2;
constexpr size_t OFF_Wr2T = OFF_Wr1T + (size_t)6144 * 1536 * 2;
constexpr size_t OFF_XS   = OFF_Wr2T + (size_t)768 * 6144 * 2;
constexpr size_t OFF_XE   = OFF_XS + (size_t)512 * 768 * 2;
constexpr size_t OFF_HS1  = OFF_XE + (size_t)512 * 768 * 2;
constexpr size_t OFF_HE1  = OFF_HS1 + (size_t)512 * 3072 * 2;
constexpr size_t OFF_CAT  = OFF_HE1 + (size_t)512 * 3072 * 2;
constexpr size_t OFF_ENTH = OFF_CAT + (size_t)512 * 1536 * 2;
constexpr size_t OFF_ENT  = OFF_ENTH + (size_t)512 * 6144 * 2;
constexpr size_t OFF_U    = OFF_ENT + (size_t)512 * 768 * 2;
constexpr size_t OFF_V    = OFF_U + (size_t)512 * 6144 * 2;
// split-K partials: Ps(4ch)+Pe(4ch) = 12.6MB; Po(8ch) overlaps both (dead by then)
constexpr size_t OFF_PS   = OFF_V + (size_t)512 * 6144 * 2;
constexpr size_t OFF_PE   = OFF_PS + (size_t)4 * 512 * 768 * 4;
constexpr size_t OFF_PO   = OFF_PS;

extern "C" void kernel_launch(void* const* d_in, const int* in_sizes, int n_in,
                              void* d_out, int out_size, void* d_ws, size_t ws_size,
                              hipStream_t stream) {
  const float* h = (const float*)d_in[0];
  const int* span = (const int*)d_in[1];   // int inputs arrive as int32
  const float* Ws1 = (const float*)d_in[2];
  const float* bs1 = (const float*)d_in[3];
  const float* Ws2 = (const float*)d_in[4];
  const float* bs2 = (const float*)d_in[5];
  const float* We1 = (const float*)d_in[6];
  const float* be1 = (const float*)d_in[7];
  const float* We2 = (const float*)d_in[8];
  const float* be2 = (const float*)d_in[9];
  const float* Wo1 = (const float*)d_in[10];
  const float* bo1 = (const float*)d_in[11];
  const float* Wo2 = (const float*)d_in[12];
  const float* bo2 = (const float*)d_in[13];
  const float* Wr1 = (const float*)d_in[14];
  const float* br1 = (const float*)d_in[15];
  const float* Wr2 = (const float*)d_in[16];
  const float* br2 = (const float*)d_in[17];

  char* ws = (char*)d_ws;
  u16* Ws1T = (u16*)(ws + OFF_Ws1T);
  u16* Ws2T = (u16*)(ws + OFF_Ws2T);
  u16* We1T = (u16*)(ws + OFF_We1T);
  u16* We2T = (u16*)(ws + OFF_We2T);
  u16* Wo1T = (u16*)(ws + OFF_Wo1T);
  u16* Wo2T = (u16*)(ws + OFF_Wo2T);
  u16* Wr1T = (u16*)(ws + OFF_Wr1T);
  u16* Wr2T = (u16*)(ws + OFF_Wr2T);
  u16* xs   = (u16*)(ws + OFF_XS);
  u16* xe   = (u16*)(ws + OFF_XE);
  u16* hs1  = (u16*)(ws + OFF_HS1);
  u16* he1  = (u16*)(ws + OFF_HE1);
  u16* cat  = (u16*)(ws + OFF_CAT);
  u16* enth = (u16*)(ws + OFF_ENTH);
  u16* ent  = (u16*)(ws + OFF_ENT);
  u16* Ub   = (u16*)(ws + OFF_U);
  u16* Vb   = (u16*)(ws + OFF_V);
  float* Ps = (float*)(ws + OFF_PS);
  float* Pe = (float*)(ws + OFF_PE);
  float* Po = (float*)(ws + OFF_PO);

  // one merged transpose launch (tstart = cumulative 64x64 tile counts)
  TDesc td;
  td.s[0] = {Ws1, Ws1T,  768, 3072,    0};
  td.s[1] = {Ws2, Ws2T, 3072,  768,  576};
  td.s[2] = {We1, We1T,  768, 3072, 1152};
  td.s[3] = {We2, We2T, 3072,  768, 1728};
  td.s[4] = {Wo1, Wo1T, 1536, 6144, 2304};
  td.s[5] = {Wo2, Wo2T, 6144,  768, 4608};
  td.s[6] = {Wr1, Wr1T, 1536, 6144, 5760};
  td.s[7] = {Wr2, Wr2T, 6144,  768, 8064};
  k_transpose_all<<<9216, dim3(16, 16), 0, stream>>>(td);

  k_gather<<<512, 256, 0, stream>>>(h, span, xs, xe);

  // GEMM1 s&e (grouped): hs1 = relu(xs@Ws1+bs1), he1 = relu(xe@We1+be1)
  k_gemm<<<dim3(96, 1, 2), 256, 0, stream>>>(xs, xe, 768, Ws1T, We1T, 768,
      bs1, be1, hs1, he1, 3072, 768, 4, 1, 1 | 2);
  // GEMM2 s&e split-K x4 -> f32 partials
  k_gemm<<<dim3(24, 1, 8), 256, 0, stream>>>(hs1, he1, 3072, Ws2T, We2T, 3072,
      nullptr, nullptr, Ps, Pe, 768, 768, 4, 4, 4);
  k_fin_cat<<<768, 256, 0, stream>>>(Ps, Pe, bs2, be2, cat);
  // entity MLP layer 1
  k_gemm<<<dim3(192, 1, 1), 256, 0, stream>>>(cat, cat, 1536, Wo1T, Wo1T, 1536,
      bo1, bo1, enth, enth, 6144, 1536, 4, 1, 1 | 2);
  // entity MLP layer 2 split-K x8 -> f32 partials
  k_gemm<<<dim3(24, 1, 8), 256, 0, stream>>>(enth, enth, 6144, Wo2T, Wo2T, 6144,
      nullptr, nullptr, Po, Po, 768, 768, 4, 8, 4);
  k_fin_ent<<<384, 256, 0, stream>>>(Po, bo2, ent);
  // low-rank pair projections (grouped): U = ent@Wr1[:768]+br1 ; V = ent@Wr1[768:]
  k_gemm<<<dim3(192, 1, 2), 256, 0, stream>>>(ent, ent, 768, Wr1T, Wr1T + 768, 1536,
      br1, nullptr, Ub, Vb, 6144, 768, 4, 1, 2);
  // fused final pair GEMM -> out (f32)
  k_pair_gemm<<<1008, 512, 0, stream>>>(Ub, Vb, Wr2T, br2, (float*)d_out);
}

// Round 12
// 445.865 us; speedup vs baseline: 1.3566x; 1.0276x over previous
//
#include <hip/hip_runtime.h>

typedef unsigned short u16;
typedef __attribute__((ext_vector_type(8))) short short8;
typedef __attribute__((ext_vector_type(4))) short short4v;
typedef __attribute__((ext_vector_type(4))) float f32x4;

#define DEVI static __device__ __forceinline__

DEVI u16 f2bf(float f) {
  unsigned u = __builtin_bit_cast(unsigned, f);
  u += 0x7FFFu + ((u >> 16) & 1u);   // RNE
  return (u16)(u >> 16);
}

DEVI float bf2f(u16 x) {
  unsigned u = ((unsigned)x) << 16;
  return __builtin_bit_cast(float, u);
}

DEVI unsigned cvtpk(float lo, float hi) {
  unsigned r;
  asm("v_cvt_pk_bf16_f32 %0, %1, %2" : "=v"(r) : "v"(lo), "v"(hi));
  return r;
}

DEVI void glds16(const void* g, void* l) {
  __builtin_amdgcn_global_load_lds(
      (const __attribute__((address_space(1))) unsigned*)g,
      (__attribute__((address_space(3))) unsigned*)l, 16, 0, 0);
}

// ------- all 8 weight transposes + span gather in ONE launch ---------------
// blocks [0,9216): 64x64 f32 transpose tiles (float4 loads, short4 stores).
// blocks [9216,9728): gather tail -- one span row each (independent work).
struct TSeg { const float* W; u16* WT; int K, N, tstart; };
struct TDesc { TSeg s[8]; };

__global__ void k_transpose_all(TDesc d, const float* __restrict__ h,
                                const int* __restrict__ span,
                                u16* __restrict__ xs, u16* __restrict__ xe) {
  __shared__ __align__(16) float t[64][68];   // 17.4 KB, 16B-aligned rows
  int bx = blockIdx.x;
  if (bx >= 9216) {                  // gather tail
    int row = bx - 9216;             // 0..511 (b*64+n)
    int b = row >> 6;
    int s = span[row * 2 + 0];
    int e = span[row * 2 + 1];
    const float* hs = h + ((size_t)b * 512 + s) * 768;
    const float* he = h + ((size_t)b * 512 + e) * 768;
    int tid = threadIdx.y * 16 + threadIdx.x;
    for (int dd = tid; dd < 768; dd += 256) {
      xs[(size_t)row * 768 + dd] = f2bf(hs[dd]);
      xe[(size_t)row * 768 + dd] = f2bf(he[dd]);
    }
    return;
  }
  int si = 0;
#pragma unroll
  for (int k = 1; k < 8; ++k) si = (bx >= d.s[k].tstart) ? k : si;
  const float* W = d.s[si].W;
  u16* WT = d.s[si].WT;
  int K = d.s[si].K, N = d.s[si].N;
  int local = bx - d.s[si].tstart;
  int tpr = N >> 6;
  int n0 = (local % tpr) << 6;
  int k0 = (local / tpr) << 6;
  int tx = threadIdx.x;  // 0..15
  int ty = threadIdx.y;  // 0..15
#pragma unroll
  for (int r = 0; r < 4; ++r) {
    float4 v = *(const float4*)(W + (size_t)(k0 + ty * 4 + r) * N + n0 + tx * 4);
    *(float4*)&t[ty * 4 + r][tx * 4] = v;
  }
  __syncthreads();
#pragma unroll
  for (int r = 0; r < 4; ++r) {
    int nr = ty * 4 + r;
    short4v o;
    o[0] = (short)f2bf(t[tx * 4 + 0][nr]);
    o[1] = (short)f2bf(t[tx * 4 + 1][nr]);
    o[2] = (short)f2bf(t[tx * 4 + 2][nr]);
    o[3] = (short)f2bf(t[tx * 4 + 3][nr]);
    *(short4v*)(WT + (size_t)(n0 + nr) * K + k0 + tx * 4) = o;
  }
}

// ---------------- unified bf16 MFMA GEMM (grouped + split-K) ---------------
// grid.z = ngroups*nsplit; z -> (g = z/nsplit, c = z%nsplit).
// A: M x K (lda), BT: N x K (ldb). k-chunk c covers [c*kLen, (c+1)*kLen).
// flags: 1=relu, 2=bf16 out, 4=f32 partial out at C + c*M*ldc (no bias).
__global__ __launch_bounds__(256)
void k_gemm(const u16* __restrict__ A0, const u16* __restrict__ A1, int lda,
            const u16* __restrict__ B0, const u16* __restrict__ B1, int ldb,
            const float* __restrict__ bias0, const float* __restrict__ bias1,
            void* __restrict__ C0, void* __restrict__ C1, int ldc,
            int kLen, int mtiles, int nsplit, int flags) {
  __shared__ __align__(16) u16 As[128 * 64];
  __shared__ __align__(16) u16 Bs[128 * 64];
  int z = blockIdx.z;
  int g = z / nsplit, c = z - g * nsplit;
  const u16* A = (g ? A1 : A0) + c * kLen;
  const u16* BT = (g ? B1 : B0) + c * kLen;
  const float* bias = g ? bias1 : bias0;
  void* C = g ? C1 : C0;

  int tid = threadIdx.x;
  int lane = tid & 63;
  int wave = tid >> 6;
  int wr = (wave >> 1) * 64, wc = (wave & 1) * 64;
  int bx = blockIdx.x;
  int m0 = (bx % mtiles) * 128;
  int n0 = (bx / mtiles) * 128;
  const int lr = lane & 15, hi = lane >> 4;

  f32x4 acc[4][4] = {};

  for (int k0 = 0; k0 < kLen; k0 += 64) {
#pragma unroll
    for (int it = 0; it < 4; ++it) {
      int s = it * 256 + tid;
      int row = s >> 3, gg = s & 7;
      int gc = (gg ^ (row & 7)) * 8;
      glds16(A + (size_t)(m0 + row) * lda + k0 + gc, (char*)As + s * 16);
      glds16(BT + (size_t)(n0 + row) * ldb + k0 + gc, (char*)Bs + s * 16);
    }
    __syncthreads();
#pragma unroll
    for (int kk = 0; kk < 2; ++kk) {
      short8 af[4], bf[4];
      int gk = kk * 4 + hi;
#pragma unroll
      for (int m = 0; m < 4; ++m) {
        int row = wr + m * 16 + lr;
        af[m] = *(const short8*)((const char*)As + row * 128 + ((gk ^ (row & 7)) * 16));
      }
#pragma unroll
      for (int n = 0; n < 4; ++n) {
        int row = wc + n * 16 + lr;
        bf[n] = *(const short8*)((const char*)Bs + row * 128 + ((gk ^ (row & 7)) * 16));
      }
#pragma unroll
      for (int m = 0; m < 4; ++m)
#pragma unroll
        for (int n = 0; n < 4; ++n)
          acc[m][n] = __builtin_amdgcn_mfma_f32_16x16x32_bf16(af[m], bf[n], acc[m][n], 0, 0, 0);
    }
    __syncthreads();
  }

  if (flags & 4) {
    float* P = (float*)C + (size_t)c * (mtiles * 128) * ldc;
#pragma unroll
    for (int n = 0; n < 4; ++n) {
      int col = n0 + wc + n * 16 + lr;
#pragma unroll
      for (int m = 0; m < 4; ++m)
#pragma unroll
        for (int r = 0; r < 4; ++r) {
          int row = m0 + wr + m * 16 + hi * 4 + r;
          P[(size_t)row * ldc + col] = acc[m][n][r];
        }
    }
  } else {
    bool relu = flags & 1;
#pragma unroll
    for (int n = 0; n < 4; ++n) {
      int col = n0 + wc + n * 16 + lr;
      float bv = bias ? bias[col] : 0.f;
#pragma unroll
      for (int m = 0; m < 4; ++m)
#pragma unroll
        for (int r = 0; r < 4; ++r) {
          int row = m0 + wr + m * 16 + hi * 4 + r;
          float v = acc[m][n][r] + bv;
          if (relu) v = fmaxf(v, 0.f);
          ((u16*)C)[(size_t)row * ldc + col] = f2bf(v);
        }
    }
  }
}

// ---------------- split-K finalizers ---------------------------------------
__global__ void k_fin_cat(const float* __restrict__ Ps, const float* __restrict__ Pe,
                          const float* __restrict__ b0, const float* __restrict__ b1,
                          u16* __restrict__ cat) {
  int t = blockIdx.x * 256 + threadIdx.x;        // 512*1536/4 = 196608
  int row = t / 384;
  int c4 = (t - row * 384) * 4;
  const float* P = Ps;
  const float* bias = b0;
  int lc = c4;
  if (c4 >= 768) { P = Pe; bias = b1; lc = c4 - 768; }
  f32x4 s = {};
#pragma unroll
  for (int ch = 0; ch < 4; ++ch)
    s += *(const f32x4*)(P + ((size_t)ch * 512 + row) * 768 + lc);
#pragma unroll
  for (int e = 0; e < 4; ++e)
    cat[(size_t)row * 1536 + c4 + e] = f2bf(fmaxf(s[e] + bias[lc + e], 0.f));
}

__global__ void k_fin_ent(const float* __restrict__ Po,
                          const float* __restrict__ bias,
                          u16* __restrict__ ent) {
  int t = blockIdx.x * 256 + threadIdx.x;        // 512*768/4 = 98304
  int row = t / 192;
  int c4 = (t - row * 192) * 4;
  f32x4 s = {};
#pragma unroll
  for (int ch = 0; ch < 8; ++ch)
    s += *(const f32x4*)(Po + ((size_t)ch * 512 + row) * 768 + c4);
#pragma unroll
  for (int e = 0; e < 4; ++e)
    ent[(size_t)row * 768 + c4 + e] = f2bf(s[e] + bias[c4 + e]);
}

// ---------------- fused pair GEMM: out = relu(U[i]+V[j]) @ Wr2 + br2 -------
// r11 geometry (BM=128, BN=192, BK=64, 512 thr / 8 waves, 64x48 wave tile,
// LDS 64KB -> 2 blocks/CU, grid 1008 = 98.4% 2-round fill) with T4 applied:
// barrier #1 is lgkm-only (no vmcnt drain); B(t) completion guaranteed at
// barrier #2 via COUNTED s_waitcnt vmcnt(7) (7 = this step's 4 UV loads +
// 3 glds; all need-drained ops are strictly older -> safe under splits).
// Last step uses vmcnt(0). B dbuf makes the counted form legal.
__global__ __launch_bounds__(512, 4)
void k_pair_gemm(const u16* __restrict__ U, const u16* __restrict__ V,
                 const u16* __restrict__ Wr2T,  // 768 x 6144 bf16
                 const float* __restrict__ br2,
                 float* __restrict__ out) {
  __shared__ __align__(16) u16 As[128 * 64];       // 16 KB
  __shared__ __align__(16) u16 Bs[2][192 * 64];    // 48 KB
  int tid = threadIdx.x;
  int lane = tid & 63;
  int wave = tid >> 6;          // 0..7
  int wr = (wave >> 2) * 64;    // 0,64
  int wc = (wave & 3) * 48;     // 0,48,96,144
  const int lr = lane & 15, hi = lane >> 4;

  // XCD swizzle: nwg = 1008 = 8*126 (divisible -> simple bijective form)
  int orig = blockIdx.x;
  int wgid = (orig & 7) * 126 + (orig >> 3);
  int mt = wgid % 252;
  int nt = wgid / 252;          // 0..3
  int m0 = mt * 128, n0 = nt * 192;

  // A-build mapping: thread owns row r, col-group q (16 cols of 64)
  int r = tid >> 2, q = tid & 3;
  int mrow = m0 + r;
  int b = mrow / 4032;
  int p = mrow - b * 4032;
  int i = p / 63;
  int j0 = p - i * 63;
  int j = j0 + (j0 >= i ? 1 : 0);
  const u16* uR = U + (size_t)(b * 64 + i) * 6144 + q * 16;
  const u16* vR = V + (size_t)(b * 64 + j) * 6144 + q * 16;
  char* aw0 = (char*)As + r * 128 + (((q * 2 + 0) ^ (r & 7)) * 16);
  char* aw1 = (char*)As + r * 128 + (((q * 2 + 1) ^ (r & 7)) * 16);

  f32x4 acc[4][3] = {};

  auto stageB = [&](int t, int buf) {
#pragma unroll
    for (int it = 0; it < 3; ++it) {
      int s = it * 512 + tid;      // 1536 granules of the 192x64 tile
      int row = s >> 3, g = s & 7;
      int gc = (g ^ (row & 7)) * 8;
      glds16(Wr2T + (size_t)(n0 + row) * 6144 + t * 64 + gc,
             (char*)Bs[buf] + s * 16);
    }
  };

  // prologue: B(0) staged, UV(0) in regs
  stageB(0, 0);
  short8 ua = *(const short8*)(uR);
  short8 ub = *(const short8*)(uR + 8);
  short8 vva = *(const short8*)(vR);
  short8 vvb = *(const short8*)(vR + 8);

  for (int t = 0; t < 96; ++t) {
    // build A(t) fragment in regs (16 elems -> 8 packed u32)
    unsigned w0[4], w1[4];
#pragma unroll
    for (int e = 0; e < 4; ++e) {
      float a0 = fmaxf(bf2f((u16)ua[2 * e])     + bf2f((u16)vva[2 * e]), 0.f);
      float a1 = fmaxf(bf2f((u16)ua[2 * e + 1]) + bf2f((u16)vva[2 * e + 1]), 0.f);
      w0[e] = cvtpk(a0, a1);
      float b0 = fmaxf(bf2f((u16)ub[2 * e])     + bf2f((u16)vvb[2 * e]), 0.f);
      float b1 = fmaxf(bf2f((u16)ub[2 * e + 1]) + bf2f((u16)vvb[2 * e + 1]), 0.f);
      w1[e] = cvtpk(b0, b1);
    }
    // #1: lgkm-only barrier -- all waves' LDS reads of As/Bs[t&1] done;
    // glds stay in flight (T4: no vmcnt drain here)
    asm volatile("s_waitcnt lgkmcnt(0)\n\ts_barrier" ::: "memory");
    *(uint4*)aw0 = *(uint4*)w0;          // swizzled A writes
    *(uint4*)aw1 = *(uint4*)w1;
    if (t + 1 < 96) {                    // prefetch t+1 (flies across MFMA(t))
      ua  = *(const short8*)(uR + (t + 1) * 64);
      ub  = *(const short8*)(uR + (t + 1) * 64 + 8);
      vva = *(const short8*)(vR + (t + 1) * 64);
      vvb = *(const short8*)(vR + (t + 1) * 64 + 8);
      stageB(t + 1, (t + 1) & 1);
      // #2: counted wait -- oldest-beyond-7 (= B(t) glds) drained; this
      // step's 7 prefetch ops (4 UV + 3 glds) stay in flight across MFMA(t)
      asm volatile("s_waitcnt vmcnt(7) lgkmcnt(0)\n\ts_barrier" ::: "memory");
    } else {
      asm volatile("s_waitcnt vmcnt(0) lgkmcnt(0)\n\ts_barrier" ::: "memory");
    }
    __builtin_amdgcn_sched_barrier(0);

    const u16* Bc = Bs[t & 1];
#pragma unroll
    for (int kk = 0; kk < 2; ++kk) {
      short8 af[4], bf[3];
      int gk = kk * 4 + hi;
#pragma unroll
      for (int m = 0; m < 4; ++m) {
        int row = wr + m * 16 + lr;
        af[m] = *(const short8*)((const char*)As + row * 128 + ((gk ^ (row & 7)) * 16));
      }
#pragma unroll
      for (int n = 0; n < 3; ++n) {
        int row = wc + n * 16 + lr;
        bf[n] = *(const short8*)((const char*)Bc + row * 128 + ((gk ^ (row & 7)) * 16));
      }
#pragma unroll
      for (int m = 0; m < 4; ++m)
#pragma unroll
        for (int n = 0; n < 3; ++n)
          acc[m][n] = __builtin_amdgcn_mfma_f32_16x16x32_bf16(af[m], bf[n], acc[m][n], 0, 0, 0);
    }
  }

#pragma unroll
  for (int n = 0; n < 3; ++n) {
    int col = n0 + wc + n * 16 + lr;
    float bv = br2[col];
#pragma unroll
    for (int m = 0; m < 4; ++m)
#pragma unroll
      for (int rg = 0; rg < 4; ++rg) {
        int row = m0 + wr + m * 16 + hi * 4 + rg;
        out[(size_t)row * 768 + col] = acc[m][n][rg] + bv;
      }
  }
}

// ---------------- workspace layout (bytes) ---------------------------------
constexpr size_t OFF_Ws1T = 0;
constexpr size_t OFF_Ws2T = OFF_Ws1T + (size_t)3072 * 768 * 2;
constexpr size_t OFF_We1T = OFF_Ws2T + (size_t)768 * 3072 * 2;
constexpr size_t OFF_We2T = OFF_We1T + (size_t)3072 * 768 * 2;
constexpr size_t OFF_Wo1T = OFF_We2T + (size_t)768 * 3072 * 2;
constexpr size_t OFF_Wo2T = OFF_Wo1T + (size_t)6144 * 1536 * 2;
constexpr size_t OFF_Wr1T = OFF_Wo2T + (size_t)768 * 6144 * 2;
constexpr size_t OFF_Wr2T = OFF_Wr1T + (size_t)6144 * 1536 * 2;
constexpr size_t OFF_XS   = OFF_Wr2T + (size_t)768 * 6144 * 2;
constexpr size_t OFF_XE   = OFF_XS + (size_t)512 * 768 * 2;
constexpr size_t OFF_HS1  = OFF_XE + (size_t)512 * 768 * 2;
constexpr size_t OFF_HE1  = OFF_HS1 + (size_t)512 * 3072 * 2;
constexpr size_t OFF_CAT  = OFF_HE1 + (size_t)512 * 3072 * 2;
constexpr size_t OFF_ENTH = OFF_CAT + (size_t)512 * 1536 * 2;
constexpr size_t OFF_ENT  = OFF_ENTH + (size_t)512 * 6144 * 2;
constexpr size_t OFF_U    = OFF_ENT + (size_t)512 * 768 * 2;
constexpr size_t OFF_V    = OFF_U + (size_t)512 * 6144 * 2;
// split-K partials: Ps(4ch)+Pe(4ch) = 12.6MB; Po(8ch) overlaps both (dead by then)
constexpr size_t OFF_PS   = OFF_V + (size_t)512 * 6144 * 2;
constexpr size_t OFF_PE   = OFF_PS + (size_t)4 * 512 * 768 * 4;
constexpr size_t OFF_PO   = OFF_PS;

extern "C" void kernel_launch(void* const* d_in, const int* in_sizes, int n_in,
                              void* d_out, int out_size, void* d_ws, size_t ws_size,
                              hipStream_t stream) {
  const float* h = (const float*)d_in[0];
  const int* span = (const int*)d_in[1];   // int inputs arrive as int32
  const float* Ws1 = (const float*)d_in[2];
  const float* bs1 = (const float*)d_in[3];
  const float* Ws2 = (const float*)d_in[4];
  const float* bs2 = (const float*)d_in[5];
  const float* We1 = (const float*)d_in[6];
  const float* be1 = (const float*)d_in[7];
  const float* We2 = (const float*)d_in[8];
  const float* be2 = (const float*)d_in[9];
  const float* Wo1 = (const float*)d_in[10];
  const float* bo1 = (const float*)d_in[11];
  const float* Wo2 = (const float*)d_in[12];
  const float* bo2 = (const float*)d_in[13];
  const float* Wr1 = (const float*)d_in[14];
  const float* br1 = (const float*)d_in[15];
  const float* Wr2 = (const float*)d_in[16];
  const float* br2 = (const float*)d_in[17];

  char* ws = (char*)d_ws;
  u16* Ws1T = (u16*)(ws + OFF_Ws1T);
  u16* Ws2T = (u16*)(ws + OFF_Ws2T);
  u16* We1T = (u16*)(ws + OFF_We1T);
  u16* We2T = (u16*)(ws + OFF_We2T);
  u16* Wo1T = (u16*)(ws + OFF_Wo1T);
  u16* Wo2T = (u16*)(ws + OFF_Wo2T);
  u16* Wr1T = (u16*)(ws + OFF_Wr1T);
  u16* Wr2T = (u16*)(ws + OFF_Wr2T);
  u16* xs   = (u16*)(ws + OFF_XS);
  u16* xe   = (u16*)(ws + OFF_XE);
  u16* hs1  = (u16*)(ws + OFF_HS1);
  u16* he1  = (u16*)(ws + OFF_HE1);
  u16* cat  = (u16*)(ws + OFF_CAT);
  u16* enth = (u16*)(ws + OFF_ENTH);
  u16* ent  = (u16*)(ws + OFF_ENT);
  u16* Ub   = (u16*)(ws + OFF_U);
  u16* Vb   = (u16*)(ws + OFF_V);
  float* Ps = (float*)(ws + OFF_PS);
  float* Pe = (float*)(ws + OFF_PE);
  float* Po = (float*)(ws + OFF_PO);

  // merged transpose + gather launch (tstart = cumulative 64x64 tile counts)
  TDesc td;
  td.s[0] = {Ws1, Ws1T,  768, 3072,    0};
  td.s[1] = {Ws2, Ws2T, 3072,  768,  576};
  td.s[2] = {We1, We1T,  768, 3072, 1152};
  td.s[3] = {We2, We2T, 3072,  768, 1728};
  td.s[4] = {Wo1, Wo1T, 1536, 6144, 2304};
  td.s[5] = {Wo2, Wo2T, 6144,  768, 4608};
  td.s[6] = {Wr1, Wr1T, 1536, 6144, 5760};
  td.s[7] = {Wr2, Wr2T, 6144,  768, 8064};
  k_transpose_all<<<9728, dim3(16, 16), 0, stream>>>(td, h, span, xs, xe);

  // GEMM1 s&e (grouped): hs1 = relu(xs@Ws1+bs1), he1 = relu(xe@We1+be1)
  k_gemm<<<dim3(96, 1, 2), 256, 0, stream>>>(xs, xe, 768, Ws1T, We1T, 768,
      bs1, be1, hs1, he1, 3072, 768, 4, 1, 1 | 2);
  // GEMM2 s&e split-K x4 -> f32 partials
  k_gemm<<<dim3(24, 1, 8), 256, 0, stream>>>(hs1, he1, 3072, Ws2T, We2T, 3072,
      nullptr, nullptr, Ps, Pe, 768, 768, 4, 4, 4);
  k_fin_cat<<<768, 256, 0, stream>>>(Ps, Pe, bs2, be2, cat);
  // entity MLP layer 1
  k_gemm<<<dim3(192, 1, 1), 256, 0, stream>>>(cat, cat, 1536, Wo1T, Wo1T, 1536,
      bo1, bo1, enth, enth, 6144, 1536, 4, 1, 1 | 2);
  // entity MLP layer 2 split-K x8 -> f32 partials
  k_gemm<<<dim3(24, 1, 8), 256, 0, stream>>>(enth, enth, 6144, Wo2T, Wo2T, 6144,
      nullptr, nullptr, Po, Po, 768, 768, 4, 8, 4);
  k_fin_ent<<<384, 256, 0, stream>>>(Po, bo2, ent);
  // low-rank pair projections (grouped): U = ent@Wr1[:768]+br1 ; V = ent@Wr1[768:]
  k_gemm<<<dim3(192, 1, 2), 256, 0, stream>>>(ent, ent, 768, Wr1T, Wr1T + 768, 1536,
      br1, nullptr, Ub, Vb, 6144, 768, 4, 1, 2);
  // fused final pair GEMM -> out (f32)
  k_pair_gemm<<<1008, 512, 0, stream>>>(Ub, Vb, Wr2T, br2, (float*)d_out);
}